// Round 6
// baseline (450.315 us; speedup 1.0000x reference)
//
#include <hip/hip_runtime.h>

#define N_USERS 100000
#define N_ITEMS 50000
#define N_NODES 150000
#define EMB_DIM 64
#define N_EDGES 4800000
#define N_LAYERS 3

#define NB 586            // ceil(150000 / 256) buckets, bucket = row >> 8
#define NBP1 (NB + 1)
#define PA_EDGES 8192     // edges per pass_a block (own region in tmp)
#define PA_BLOCKS ((N_EDGES + PA_EDGES - 1) / PA_EDGES)   // 586
#define PB_CAP 9088       // LDS record capacity in pass_b (mean 8191, +9.9 sigma)

#define VAL_ENC (32.0f * 16383.0f)
#define VAL_DEC (1.0f / (32.0f * 16383.0f))

__device__ __forceinline__ ushort f2bf(float f) {
    unsigned int b = __float_as_uint(f);
    unsigned int r = (b + 0x7FFFu + ((b >> 16) & 1u)) >> 16;   // RNE
    return (ushort)r;
}
__device__ __forceinline__ float bf2f(ushort u) {
    return __uint_as_float(((unsigned int)u) << 16);
}
__device__ __forceinline__ uint pack_cv(int c, float v) {
    uint vq = (uint)(v * VAL_ENC + 0.5f);
    if (vq > 16383u) vq = 16383u;
    return ((uint)c << 14) | vq;
}

// ---------------------------------------------------------------------------
// init: x0 = bf16(concat(emb_user, emb_item))
// ---------------------------------------------------------------------------
__global__ void init_kernel(const float* __restrict__ emb_user,
                            const float* __restrict__ emb_item,
                            ushort* __restrict__ x0) {
    int i = blockIdx.x * blockDim.x + threadIdx.x;
    const int total = N_NODES * EMB_DIM / 4;
    if (i >= total) return;
    const int user_f4 = N_USERS * EMB_DIM / 4;
    float4 v;
    if (i < user_f4) v = reinterpret_cast<const float4*>(emb_user)[i];
    else             v = reinterpret_cast<const float4*>(emb_item)[i - user_f4];
    ushort4 h;
    h.x = f2bf(v.x); h.y = f2bf(v.y); h.z = f2bf(v.z); h.w = f2bf(v.w);
    reinterpret_cast<ushort4*>(x0)[i] = h;
}

// ---------------------------------------------------------------------------
// pass_a: each block bucket-sorts its 8192-edge chunk in LDS, streams the
// sorted image to its OWN region of tmp (coalesced full-line writes),
// writes its offs row, and accumulates global bucket_cnt (replaces hist).
// ---------------------------------------------------------------------------
__global__ void __launch_bounds__(512)
pass_a(const int* __restrict__ row, const int* __restrict__ col,
       const float* __restrict__ val,
       int* __restrict__ bucket_cnt,
       uint2* __restrict__ tmp, int* __restrict__ offs) {
    __shared__ uint2 rec[PA_EDGES];      // 64 KB
    __shared__ int cnt[NB];
    __shared__ int cur[NB];
    __shared__ int scan_tmp[512];
    int t = threadIdx.x;
    int blk = blockIdx.x;
    int e0 = blk * PA_EDGES;
    int ecnt = N_EDGES - e0;
    if (ecnt > PA_EDGES) ecnt = PA_EDGES;
    int i4cnt = ecnt >> 2;
    const int4*   rp = reinterpret_cast<const int4*>(row) + (e0 >> 2);
    const int4*   cp = reinterpret_cast<const int4*>(col) + (e0 >> 2);
    const float4* vp = reinterpret_cast<const float4*>(val) + (e0 >> 2);

    for (int b = t; b < NB; b += 512) cnt[b] = 0;
    __syncthreads();
    // phase 1: count
    for (int i = t; i < i4cnt; i += 512) {
        int4 r = rp[i];
        atomicAdd(&cnt[r.x >> 8], 1);
        atomicAdd(&cnt[r.y >> 8], 1);
        atomicAdd(&cnt[r.z >> 8], 1);
        atomicAdd(&cnt[r.w >> 8], 1);
    }
    __syncthreads();
    // accumulate global bucket counts (replaces the old hist kernel)
    for (int b = t; b < NB; b += 512) {
        int c = cnt[b];
        if (c) atomicAdd(&bucket_cnt[b], c);
    }
    // phase 2: exclusive scan of cnt -> cur + offs row (pairwise, 512-wide)
    int i0 = 2 * t, i1 = 2 * t + 1;
    int a0 = (i0 < NB) ? cnt[i0] : 0;
    int a1 = (i1 < NB) ? cnt[i1] : 0;
    scan_tmp[t] = a0 + a1;
    __syncthreads();
    for (int off = 1; off < 512; off <<= 1) {
        int x = (t >= off) ? scan_tmp[t - off] : 0;
        __syncthreads();
        scan_tmp[t] += x;
        __syncthreads();
    }
    int pair_excl = scan_tmp[t] - (a0 + a1);
    int* offs_row = offs + (size_t)blk * NBP1;
    if (i0 < NB) { cur[i0] = pair_excl;      offs_row[i0] = pair_excl; }
    if (i1 < NB) { cur[i1] = pair_excl + a0; offs_row[i1] = pair_excl + a0; }
    if (t == 0) offs_row[NB] = ecnt;
    __syncthreads();
    // phase 3: insert records into LDS image
    for (int i = t; i < i4cnt; i += 512) {
        int4 r = rp[i];
        int4 c = cp[i];
        float4 v = vp[i];
        int p;
        p = atomicAdd(&cur[r.x >> 8], 1); rec[p] = make_uint2(pack_cv(c.x, v.x), (uint)(r.x & 255));
        p = atomicAdd(&cur[r.y >> 8], 1); rec[p] = make_uint2(pack_cv(c.y, v.y), (uint)(r.y & 255));
        p = atomicAdd(&cur[r.z >> 8], 1); rec[p] = make_uint2(pack_cv(c.z, v.z), (uint)(r.z & 255));
        p = atomicAdd(&cur[r.w >> 8], 1); rec[p] = make_uint2(pack_cv(c.w, v.w), (uint)(r.w & 255));
    }
    __syncthreads();
    // phase 4: stream LDS image to own global region (coalesced)
    uint2* dst = tmp + (size_t)blk * PA_EDGES;
    for (int i = t; i < ecnt; i += 512) dst[i] = rec[i];
}

// ---------------------------------------------------------------------------
// bucket_scan: exclusive scan of 586 bucket counts (one 1024-thread block)
// ---------------------------------------------------------------------------
__global__ void bucket_scan(const int* __restrict__ bucket_cnt,
                            int* __restrict__ bucket_ptr,
                            int* __restrict__ row_ptr) {
    __shared__ int lds[1024];
    int t = threadIdx.x;
    int v = (t < NB) ? bucket_cnt[t] : 0;
    lds[t] = v;
    __syncthreads();
    for (int off = 1; off < 1024; off <<= 1) {
        int x = (t >= off) ? lds[t - off] : 0;
        __syncthreads();
        lds[t] += x;
        __syncthreads();
    }
    int incl = lds[t];
    if (t < NB) bucket_ptr[t] = incl - v;
    if (t == NB - 1) bucket_ptr[NB] = incl;
    if (t == 0) row_ptr[N_NODES] = N_EDGES;
}

// ---------------------------------------------------------------------------
// pass_b: block per bucket. Preload offs columns -> gather 586 runs into a
// LDS record buffer -> count/scan rows -> row_ptr + scatter cv (L2-resident).
// ---------------------------------------------------------------------------
__global__ void __launch_bounds__(512)
pass_b(const int* __restrict__ bucket_ptr, const int* __restrict__ offs,
       const uint2* __restrict__ tmp,
       int* __restrict__ row_ptr, uint* __restrict__ cv) {
    __shared__ uint2 rec[PB_CAP];        // 72.7 KB
    __shared__ int oa[PA_BLOCKS];
    __shared__ int ob[PA_BLOCKS];
    __shared__ int cnt[256];
    __shared__ int cur[256];
    __shared__ int wtot[4];
    __shared__ int lds_total;
    int t = threadIdx.x;
    int b = blockIdx.x;
    int lane = t & 63, wv = t >> 6;      // 8 waves
    if (t < 256) cnt[t] = 0;
    if (t == 0) lds_total = 0;
    // preload both offs columns (independent scattered loads)
    for (int j = t; j < PA_BLOCKS; j += 512) {
        oa[j] = offs[(size_t)j * NBP1 + b];
        ob[j] = offs[(size_t)j * NBP1 + b + 1];
    }
    __syncthreads();
    // gather runs into LDS (wave per run, round-robin)
    for (int j = wv; j < PA_BLOCKS; j += 8) {
        int s = oa[j];
        int n = ob[j] - s;
        if (n <= 0) continue;
        int base = 0;
        if (lane == 0) base = atomicAdd(&lds_total, n);
        base = __shfl(base, 0, 64);
        const uint2* src = tmp + (size_t)j * PA_EDGES + s;
        for (int k = lane; k < n; k += 64) rec[base + k] = src[k];
    }
    __syncthreads();
    int total = lds_total;
    // count rows
    for (int i = t; i < total; i += 512) atomicAdd(&cnt[rec[i].y], 1);
    __syncthreads();
    // exclusive scan of 256 row counts (threads 0..255; barriers uniform)
    int v = (t < 256) ? cnt[t] : 0;
    int x = v;
    for (int off = 1; off < 64; off <<= 1) {
        int y = __shfl_up(x, off, 64);
        if (lane >= off) x += y;
    }
    if (t < 256 && lane == 63) wtot[wv] = x;
    __syncthreads();
    if (t < 256) {
        int woff = 0;
        for (int w = 0; w < wv; ++w) woff += wtot[w];
        int excl = woff + x - v;
        int base = bucket_ptr[b];
        int gr = (b << 8) + t;
        if (gr < N_NODES) row_ptr[gr] = base + excl;
        cur[t] = base + excl;
    }
    __syncthreads();
    // scatter cv (writes land in this bucket's ~33 KB L2-resident region)
    for (int i = t; i < total; i += 512) {
        uint2 r = rec[i];
        int pos = atomicAdd(&cur[r.y], 1);
        cv[pos] = r.x;
    }
}

// ---------------------------------------------------------------------------
// gather SpMM: one wave per row. Wave-wide cvp preload (64 edges/round),
// shfl-distributed addresses, 4 independent gathers per unrolled iter.
// MODE 0: y = bf16(A*x)
// MODE 1: out = (emb + y1 + y2 + A*x) * 0.25   (fused final combine)
// ---------------------------------------------------------------------------
template <int MODE>
__global__ void spmm_kernel(const int* __restrict__ row_ptr,
                            const uint* __restrict__ cvp,
                            const ushort* __restrict__ x,
                            ushort* __restrict__ y,
                            const float* __restrict__ emb_user,
                            const float* __restrict__ emb_item,
                            const ushort* __restrict__ y1,
                            const ushort* __restrict__ y2,
                            float* __restrict__ out) {
    int wave = threadIdx.x >> 6;
    int lane = threadIdx.x & 63;
    int r = blockIdx.x * 4 + wave;
    if (r >= N_NODES) return;
    int g = lane >> 4;   // edge-slot group
    int d = lane & 15;   // ushort4 slot within the embedding row
    int s = row_ptr[r];
    int deg = row_ptr[r + 1] - s;
    const ushort4* xu = reinterpret_cast<const ushort4*>(x);
    float4 a4 = make_float4(0.f, 0.f, 0.f, 0.f);

    for (int base = 0; base < deg; base += 64) {
        int nload = deg - base;
        if (nload > 64) nload = 64;
        uint mycv = cvp[s + base + (lane < nload ? lane : nload - 1)];
        int rounds4 = (nload + 15) >> 4;
        for (int k4 = 0; k4 < rounds4; ++k4) {
            int i0 = (k4 << 4) + g;
            int i1 = i0 + 4, i2 = i0 + 8, i3 = i0 + 12;
            uint c0 = __shfl(mycv, i0, 64);
            uint c1 = __shfl(mycv, i1, 64);
            uint c2 = __shfl(mycv, i2, 64);
            uint c3 = __shfl(mycv, i3, 64);
            ushort4 xv0 = xu[((c0 >> 14) << 4) + d];
            ushort4 xv1 = xu[((c1 >> 14) << 4) + d];
            ushort4 xv2 = xu[((c2 >> 14) << 4) + d];
            ushort4 xv3 = xu[((c3 >> 14) << 4) + d];
            float v0 = (i0 < nload) ? (float)(c0 & 16383u) * VAL_DEC : 0.f;
            float v1 = (i1 < nload) ? (float)(c1 & 16383u) * VAL_DEC : 0.f;
            float v2 = (i2 < nload) ? (float)(c2 & 16383u) * VAL_DEC : 0.f;
            float v3 = (i3 < nload) ? (float)(c3 & 16383u) * VAL_DEC : 0.f;
            a4.x += v0 * bf2f(xv0.x); a4.y += v0 * bf2f(xv0.y);
            a4.z += v0 * bf2f(xv0.z); a4.w += v0 * bf2f(xv0.w);
            a4.x += v1 * bf2f(xv1.x); a4.y += v1 * bf2f(xv1.y);
            a4.z += v1 * bf2f(xv1.z); a4.w += v1 * bf2f(xv1.w);
            a4.x += v2 * bf2f(xv2.x); a4.y += v2 * bf2f(xv2.y);
            a4.z += v2 * bf2f(xv2.z); a4.w += v2 * bf2f(xv2.w);
            a4.x += v3 * bf2f(xv3.x); a4.y += v3 * bf2f(xv3.y);
            a4.z += v3 * bf2f(xv3.z); a4.w += v3 * bf2f(xv3.w);
        }
    }
    for (int off = 16; off <= 32; off <<= 1) {
        a4.x += __shfl_xor(a4.x, off, 64);
        a4.y += __shfl_xor(a4.y, off, 64);
        a4.z += __shfl_xor(a4.z, off, 64);
        a4.w += __shfl_xor(a4.w, off, 64);
    }
    if (g == 0) {
        int o = (r << 4) + d;
        if (MODE == 0) {
            ushort4 h;
            h.x = f2bf(a4.x); h.y = f2bf(a4.y); h.z = f2bf(a4.z); h.w = f2bf(a4.w);
            reinterpret_cast<ushort4*>(y)[o] = h;
        } else {
            const float4* eb = (r < N_USERS)
                ? reinterpret_cast<const float4*>(emb_user) + ((size_t)r << 4)
                : reinterpret_cast<const float4*>(emb_item) + ((size_t)(r - N_USERS) << 4);
            float4 ev = eb[d];
            ushort4 h1 = reinterpret_cast<const ushort4*>(y1)[o];
            ushort4 h2 = reinterpret_cast<const ushort4*>(y2)[o];
            float4 rr;
            rr.x = (ev.x + bf2f(h1.x) + bf2f(h2.x) + a4.x) * 0.25f;
            rr.y = (ev.y + bf2f(h1.y) + bf2f(h2.y) + a4.y) * 0.25f;
            rr.z = (ev.z + bf2f(h1.z) + bf2f(h2.z) + a4.z) * 0.25f;
            rr.w = (ev.w + bf2f(h1.w) + bf2f(h2.w) + a4.w) * 0.25f;
            reinterpret_cast<float4*>(out)[o] = rr;
        }
    }
}

// ---------------------------------------------------------------------------
// fallback (round-0) atomic path, used only if ws_size is too small
// ---------------------------------------------------------------------------
__global__ void fb_init(const float* __restrict__ emb_user,
                        const float* __restrict__ emb_item,
                        float* __restrict__ cur, float* __restrict__ acc) {
    int i = blockIdx.x * blockDim.x + threadIdx.x;
    const int total = N_NODES * EMB_DIM / 4;
    if (i >= total) return;
    const int user_f4 = N_USERS * EMB_DIM / 4;
    float4 v;
    if (i < user_f4) v = reinterpret_cast<const float4*>(emb_user)[i];
    else             v = reinterpret_cast<const float4*>(emb_item)[i - user_f4];
    reinterpret_cast<float4*>(cur)[i] = v;
    reinterpret_cast<float4*>(acc)[i] = v;
}

__global__ void scatter_kernel(const int* __restrict__ edge_row,
                               const int* __restrict__ edge_col,
                               const float* __restrict__ edge_val,
                               const float* __restrict__ x,
                               float* __restrict__ y) {
    long long tid = (long long)blockIdx.x * blockDim.x + threadIdx.x;
    long long e = tid >> 4;
    int sub = (int)(tid & 15);
    if (e >= N_EDGES) return;
    int r = edge_row[e];
    int c = edge_col[e];
    float v = edge_val[e];
    float4 xv = reinterpret_cast<const float4*>(x)[(long long)c * 16 + sub];
    float* dst = y + ((long long)r * EMB_DIM + sub * 4);
    atomicAdd(dst + 0, v * xv.x);
    atomicAdd(dst + 1, v * xv.y);
    atomicAdd(dst + 2, v * xv.z);
    atomicAdd(dst + 3, v * xv.w);
}

template <bool FINAL>
__global__ void add_kernel(const float* __restrict__ nxt, float* __restrict__ acc) {
    int i = blockIdx.x * blockDim.x + threadIdx.x;
    const int total = N_NODES * EMB_DIM / 4;
    if (i >= total) return;
    float4 a = reinterpret_cast<float4*>(acc)[i];
    float4 b = reinterpret_cast<const float4*>(nxt)[i];
    a.x += b.x; a.y += b.y; a.z += b.z; a.w += b.w;
    if (FINAL) {
        const float s = 1.0f / (N_LAYERS + 1);
        a.x *= s; a.y *= s; a.z *= s; a.w *= s;
    }
    reinterpret_cast<float4*>(acc)[i] = a;
}

// ---------------------------------------------------------------------------
extern "C" void kernel_launch(void* const* d_in, const int* in_sizes, int n_in,
                              void* d_out, int out_size, void* d_ws, size_t ws_size,
                              hipStream_t stream) {
    const float* emb_user = (const float*)d_in[0];
    const float* emb_item = (const float*)d_in[1];
    const int*   edge_row = (const int*)d_in[2];
    const int*   edge_col = (const int*)d_in[3];
    const float* edge_val = (const float*)d_in[4];
    float* out = (float*)d_out;

    const size_t x_bytes = (size_t)N_NODES * EMB_DIM * sizeof(ushort);   // 19.2 MB
    const size_t tmp_bytes = (size_t)PA_BLOCKS * PA_EDGES * sizeof(uint2); // 38.4 MB

    // ---- workspace layout ----
    char* base = (char*)d_ws;
    uint*  cv  = (uint*)base;                                  // 19.2 MB
    uint2* tmp = (uint2*)(base + (size_t)N_EDGES * 4);         // 38.4 MB
    int*   offs = (int*)((char*)tmp + tmp_bytes);              // 1.38 MB
    ushort* x2 = (ushort*)((char*)offs + (size_t)PA_BLOCKS * NBP1 * 4); // 19.2 MB
    char* meta = (char*)x2 + x_bytes;
    int* row_ptr    = (int*)meta;                              // N_NODES+1
    int* bucket_cnt = row_ptr + N_NODES + 2;
    int* bucket_ptr = bucket_cnt + NB;                         // NB+1
    size_t need = (size_t)((char*)(bucket_ptr + NBP1) - base);
    // x0/x1 alias tmp (dead after pass_b; init runs after)
    ushort* x0 = (ushort*)tmp;
    ushort* x1 = (ushort*)((char*)tmp + x_bytes);

    const int BT = 256;
    const int total_f4 = N_NODES * EMB_DIM / 4;
    const int grid_f4 = (total_f4 + BT - 1) / BT;

    if (ws_size >= need) {
        // ---- two-pass LDS counting sort -> row-sorted packed cv + row_ptr ----
        hipMemsetAsync(bucket_cnt, 0, NB * sizeof(int), stream);
        pass_a<<<PA_BLOCKS, 512, 0, stream>>>(edge_row, edge_col, edge_val,
                                              bucket_cnt, tmp, offs);
        bucket_scan<<<1, 1024, 0, stream>>>(bucket_cnt, bucket_ptr, row_ptr);
        pass_b<<<NB, 512, 0, stream>>>(bucket_ptr, offs, tmp, row_ptr, cv);

        // ---- init + 3 gather layers ----
        init_kernel<<<grid_f4, BT, 0, stream>>>(emb_user, emb_item, x0);
        const int grid_rows = (N_NODES + 3) / 4;
        spmm_kernel<0><<<grid_rows, BT, 0, stream>>>(row_ptr, cv, x0, x1,
                                                     nullptr, nullptr, nullptr, nullptr, nullptr);
        spmm_kernel<0><<<grid_rows, BT, 0, stream>>>(row_ptr, cv, x1, x2,
                                                     nullptr, nullptr, nullptr, nullptr, nullptr);
        spmm_kernel<1><<<grid_rows, BT, 0, stream>>>(row_ptr, cv, x2, nullptr,
                                                     emb_user, emb_item, x1, x2, out);
    } else {
        // ---- fallback: atomic scatter path ----
        const size_t buf_elems = (size_t)N_NODES * EMB_DIM;
        const size_t buf_bytes = buf_elems * sizeof(float);
        float* bufA = (float*)d_ws;
        float* bufB = bufA + buf_elems;
        fb_init<<<grid_f4, BT, 0, stream>>>(emb_user, emb_item, bufA, out);
        const long long scatter_threads = (long long)N_EDGES * 16;
        const int grid_sc = (int)((scatter_threads + BT - 1) / BT);
        float* cur = bufA;
        float* nxt = bufB;
        for (int layer = 0; layer < N_LAYERS; ++layer) {
            hipMemsetAsync(nxt, 0, buf_bytes, stream);
            scatter_kernel<<<grid_sc, BT, 0, stream>>>(edge_row, edge_col, edge_val, cur, nxt);
            if (layer == N_LAYERS - 1) add_kernel<true><<<grid_f4, BT, 0, stream>>>(nxt, out);
            else                        add_kernel<false><<<grid_f4, BT, 0, stream>>>(nxt, out);
            float* t = cur; cur = nxt; nxt = t;
        }
    }
}